// Round 1
// baseline (1208.541 us; speedup 1.0000x reference)
//
#include <hip/hip_runtime.h>
#include <math.h>

#define N_NODES 100000
#define N_EDGES 3200000
#define IN_F 256
#define OUT_F 64
#define LRELU_SLOPE 0.2f

// ---------------------------------------------------------------------------
// Kernel 1: h = X @ W  (100000x256 @ 256x64), fused s_src = h@a[:64],
// s_dst = h@a[64:]. Block = 256 threads = 4 waves; each wave owns one row
// (64 lanes = 64 output cols). Input rows staged in LDS; W streamed through
// L1 (64 KB total, every wave reads the same 64-float line per k).
// ---------------------------------------------------------------------------
__global__ __launch_bounds__(256) void gemm_h_kernel(
    const float* __restrict__ in, const float* __restrict__ W,
    const float* __restrict__ a, float* __restrict__ h,
    float* __restrict__ s_src, float* __restrict__ s_dst) {
  __shared__ float in_tile[4 * IN_F];
  const int r = threadIdx.x >> 6;       // wave id = local row
  const int col = threadIdx.x & 63;     // lane = output col
  const int row = blockIdx.x * 4 + r;

  // Cooperative load of 4 input rows (4*256 floats, 256 threads -> 4 each)
  const float* rowbase = in + (size_t)blockIdx.x * 4 * IN_F;
#pragma unroll
  for (int i = 0; i < 4; ++i)
    in_tile[i * IN_F + threadIdx.x] = rowbase[i * IN_F + threadIdx.x];
  __syncthreads();

  const float* tr = in_tile + r * IN_F;
  float acc = 0.f;
#pragma unroll 8
  for (int k = 0; k < IN_F; ++k)
    acc += tr[k] * W[k * OUT_F + col];

  h[(size_t)row * OUT_F + col] = acc;

  // wave-reduce acc * a_src[col], acc * a_dst[col] -> s_src[row], s_dst[row]
  float vs = acc * a[col];
  float vd = acc * a[OUT_F + col];
#pragma unroll
  for (int off = 32; off > 0; off >>= 1) {
    vs += __shfl_down(vs, off);
    vd += __shfl_down(vd, off);
  }
  if (col == 0) {
    s_src[row] = vs;
    s_dst[row] = vd;
  }
}

// ---------------------------------------------------------------------------
// Kernel 2: per-edge attention + scatter. One wave per edge; lane = feature.
//   e = exp(-leaky_relu(s_src[src] + s_dst[dst]))
//   hprime[src][:] += e * h[dst][:]   (64-lane coalesced atomicAdd)
//   rowsum[src]    += e               (lane 0)
// h (25.6 MB) is L2/L3 resident; atomics go to L2.
// ---------------------------------------------------------------------------
__global__ __launch_bounds__(256) void edge_kernel(
    const int* __restrict__ src, const int* __restrict__ dst,
    const float* __restrict__ h, const float* __restrict__ s_src,
    const float* __restrict__ s_dst, float* __restrict__ hprime,
    float* __restrict__ rowsum) {
  const int e = blockIdx.x * 4 + (threadIdx.x >> 6);
  if (e >= N_EDGES) return;
  const int lane = threadIdx.x & 63;

  const int s = src[e];
  const int d = dst[e];
  const float score = s_src[s] + s_dst[d];             // broadcast loads
  const float lr = score > 0.f ? score : LRELU_SLOPE * score;
  const float ee = expf(-lr);

  const float hv = h[(size_t)d * OUT_F + lane];
  atomicAdd(&hprime[(size_t)s * OUT_F + lane], ee * hv);
  if (lane == 0) atomicAdd(&rowsum[s], ee);
}

// ---------------------------------------------------------------------------
// Kernel 3: out = elu(hprime / rowsum), in place on d_out.
// ---------------------------------------------------------------------------
__global__ __launch_bounds__(256) void finalize_kernel(
    float* __restrict__ hprime, const float* __restrict__ rowsum) {
  const size_t i = (size_t)blockIdx.x * blockDim.x + threadIdx.x;
  const float v = hprime[i] / rowsum[i >> 6];          // rowsum broadcast/wave
  hprime[i] = v > 0.f ? v : expm1f(v);
}

extern "C" void kernel_launch(void* const* d_in, const int* in_sizes, int n_in,
                              void* d_out, int out_size, void* d_ws, size_t ws_size,
                              hipStream_t stream) {
  const float* in = (const float*)d_in[0];
  const int* edge = (const int*)d_in[1];   // int32 (JAX x64 disabled)
  const float* W = (const float*)d_in[2];
  const float* a = (const float*)d_in[3];
  float* out = (float*)d_out;

  // workspace layout (floats): h[N*64] | s_src[N] | s_dst[N] | rowsum[N]
  float* h = (float*)d_ws;
  float* s_src = h + (size_t)N_NODES * OUT_F;
  float* s_dst = s_src + N_NODES;
  float* rowsum = s_dst + N_NODES;

  hipMemsetAsync(out, 0, (size_t)N_NODES * OUT_F * sizeof(float), stream);
  hipMemsetAsync(rowsum, 0, (size_t)N_NODES * sizeof(float), stream);

  gemm_h_kernel<<<N_NODES / 4, 256, 0, stream>>>(in, W, a, h, s_src, s_dst);
  edge_kernel<<<(N_EDGES + 3) / 4, 256, 0, stream>>>(
      edge, edge + N_EDGES, h, s_src, s_dst, out, rowsum);
  finalize_kernel<<<(N_NODES * OUT_F) / 256, 256, 0, stream>>>(out, rowsum);
}

// Round 3
// 805.842 us; speedup vs baseline: 1.4997x; 1.4997x over previous
//
#include <hip/hip_runtime.h>
#include <hip/hip_bf16.h>
#include <math.h>

#define N_NODES 100000
#define N_EDGES 3200000
#define IN_F 256
#define OUT_F 64
#define LRELU_SLOPE 0.2f
#define SCAN_B 1024
#define SCAN_NBLK ((N_NODES + SCAN_B - 1) / SCAN_B)   // 98

// ---------------------------------------------------------------------------
// K1: h = X @ W (bf16 store) fused with s_src = h@a[:64], s_dst = h@a[64:].
// 32 rows/block (4 waves x 8 rows), x-tile in LDS (32 KB), W streamed from
// L1/L2 (64 KB total, 0.4 GB L2 traffic across 3125 blocks).
// ---------------------------------------------------------------------------
__global__ __launch_bounds__(256) void gemm_h_kernel(
    const float* __restrict__ in, const float* __restrict__ W,
    const float* __restrict__ a, __hip_bfloat16* __restrict__ h,
    float* __restrict__ s_src, float* __restrict__ s_dst) {
  __shared__ float xl[32 * IN_F];               // 32 KB
  const int w = threadIdx.x >> 6;               // wave id
  const int col = threadIdx.x & 63;             // lane = output col
  const int row0 = blockIdx.x * 32;

  // cooperative load of 32 input rows (8192 floats) as float4
  const float4* gx = (const float4*)(in + (size_t)row0 * IN_F);
  float4* lx = (float4*)xl;
#pragma unroll
  for (int i = 0; i < 8; ++i)
    lx[i * 256 + threadIdx.x] = gx[i * 256 + threadIdx.x];
  __syncthreads();

  const float* xr = xl + (w * 8) * IN_F;        // this wave's 8 rows
  float acc[8] = {0.f, 0.f, 0.f, 0.f, 0.f, 0.f, 0.f, 0.f};

  for (int k = 0; k < IN_F; k += 4) {
    float wv0 = W[(k + 0) * OUT_F + col];
    float wv1 = W[(k + 1) * OUT_F + col];
    float wv2 = W[(k + 2) * OUT_F + col];
    float wv3 = W[(k + 3) * OUT_F + col];
#pragma unroll
    for (int r = 0; r < 8; ++r) {
      float4 xv = *(const float4*)&xr[r * IN_F + k];   // wave-uniform b128
      acc[r] += xv.x * wv0 + xv.y * wv1 + xv.z * wv2 + xv.w * wv3;
    }
  }

  const float as = a[col];
  const float ad = a[OUT_F + col];
#pragma unroll
  for (int r = 0; r < 8; ++r) {
    const int row = row0 + w * 8 + r;
    h[(size_t)row * OUT_F + col] = __float2bfloat16(acc[r]);
    float vs = acc[r] * as;
    float vd = acc[r] * ad;
#pragma unroll
    for (int off = 32; off > 0; off >>= 1) {
      vs += __shfl_down(vs, off);
      vd += __shfl_down(vd, off);
    }
    if (col == 0) {
      s_src[row] = vs;
      s_dst[row] = vd;
    }
  }
}

// ---------------------------------------------------------------------------
// K2: histogram of src (int atomics only).
// ---------------------------------------------------------------------------
__global__ __launch_bounds__(256) void hist_kernel(
    const int* __restrict__ src, int* __restrict__ counts) {
  const int e = blockIdx.x * 256 + threadIdx.x;
  if (e < N_EDGES) atomicAdd(&counts[src[e]], 1);
}

// ---------------------------------------------------------------------------
// K3a/b/c: exclusive scan of counts -> offsets[N+1] (inclusive stored in
// offsets[1..] directly; no separate incl buffer), cursor = segment starts.
// ---------------------------------------------------------------------------
__global__ __launch_bounds__(SCAN_B) void scan1_kernel(
    const int* __restrict__ counts, int* __restrict__ offsets,
    int* __restrict__ blocksums) {
  __shared__ int tmp[SCAN_B];
  const int i = blockIdx.x * SCAN_B + threadIdx.x;
  int v = (i < N_NODES) ? counts[i] : 0;
  tmp[threadIdx.x] = v;
  __syncthreads();
  for (int off = 1; off < SCAN_B; off <<= 1) {
    int t = (threadIdx.x >= off) ? tmp[threadIdx.x - off] : 0;
    __syncthreads();
    tmp[threadIdx.x] += t;
    __syncthreads();
  }
  if (i < N_NODES) offsets[i + 1] = tmp[threadIdx.x];   // per-block inclusive
  if (threadIdx.x == SCAN_B - 1) blocksums[blockIdx.x] = tmp[threadIdx.x];
}

__global__ __launch_bounds__(128) void scan2_kernel(int* __restrict__ blocksums) {
  __shared__ int tmp[128];
  int v = (threadIdx.x < SCAN_NBLK) ? blocksums[threadIdx.x] : 0;
  tmp[threadIdx.x] = v;
  __syncthreads();
  for (int off = 1; off < 128; off <<= 1) {
    int t = (threadIdx.x >= off) ? tmp[threadIdx.x - off] : 0;
    __syncthreads();
    tmp[threadIdx.x] += t;
    __syncthreads();
  }
  if (threadIdx.x < SCAN_NBLK) blocksums[threadIdx.x] = tmp[threadIdx.x];
}

__global__ __launch_bounds__(SCAN_B) void scan3_kernel(
    const int* __restrict__ counts, const int* __restrict__ blocksums,
    int* __restrict__ offsets, int* __restrict__ cursor) {
  const int i = blockIdx.x * SCAN_B + threadIdx.x;
  if (i >= N_NODES) return;
  const int add = (blockIdx.x > 0) ? blocksums[blockIdx.x - 1] : 0;
  const int v = offsets[i + 1] + add;            // global inclusive
  offsets[i + 1] = v;
  cursor[i] = v - counts[i];                     // exclusive = segment start
  if (i == 0) offsets[0] = 0;
}

// ---------------------------------------------------------------------------
// K4: scatter dst into CSR order (only dst; ee recomputed in K5).
// ---------------------------------------------------------------------------
__global__ __launch_bounds__(256) void scatter_kernel(
    const int* __restrict__ src, const int* __restrict__ dst,
    int* __restrict__ cursor, int* __restrict__ sorted_dst) {
  const int e = blockIdx.x * 256 + threadIdx.x;
  if (e >= N_EDGES) return;
  const int p = atomicAdd(&cursor[src[e]], 1);
  sorted_dst[p] = dst[e];
}

// ---------------------------------------------------------------------------
// K5: per-node aggregation, one wave per node, NO atomics. ee recomputed
// from s_src[node] (wave-uniform) + s_dst[dst] (L2-hot gather). Fused
// finalize: out = elu(acc / rowsum).
// ---------------------------------------------------------------------------
__global__ __launch_bounds__(256) void node_aggregate_kernel(
    const int* __restrict__ offsets, const int* __restrict__ sorted_dst,
    const float* __restrict__ s_src, const float* __restrict__ s_dst,
    const __hip_bfloat16* __restrict__ h, float* __restrict__ out) {
  const int node = blockIdx.x * 4 + (threadIdx.x >> 6);
  const int lane = threadIdx.x & 63;
  if (node >= N_NODES) return;

  const int b = offsets[node];
  const int cnt = offsets[node + 1] - b;
  const float su = s_src[node];

  float acc = 0.f, rs = 0.f;
  for (int c = 0; c < cnt; c += 64) {
    const int rem = min(64, cnt - c);
    int d = 0;
    float ev = 0.f;
    if (lane < rem) {
      d = sorted_dst[b + c + lane];
      const float sc = su + s_dst[d];
      const float lr = sc > 0.f ? sc : LRELU_SLOPE * sc;
      ev = expf(-lr);
    }
    for (int i = 0; i < rem; ++i) {
      const int dd = __shfl(d, i);
      const float ef = __shfl(ev, i);
      acc += ef * __bfloat162float(h[(size_t)dd * OUT_F + lane]);
      rs += ef;
    }
  }
  const float v = acc / rs;
  out[(size_t)node * OUT_F + lane] = v > 0.f ? v : expm1f(v);
}

// ---------------------------------------------------------------------------
// Fallback path (ws too small for CSR): round-1 proven atomic pipeline,
// adapted to bf16 h. Needs only h + s_src + s_dst + rowsum = 14 MB.
// ---------------------------------------------------------------------------
__global__ __launch_bounds__(256) void edge_atomic_kernel(
    const int* __restrict__ src, const int* __restrict__ dst,
    const __hip_bfloat16* __restrict__ h, const float* __restrict__ s_src,
    const float* __restrict__ s_dst, float* __restrict__ hprime,
    float* __restrict__ rowsum) {
  const int e = blockIdx.x * 4 + (threadIdx.x >> 6);
  if (e >= N_EDGES) return;
  const int lane = threadIdx.x & 63;
  const int s = src[e];
  const int d = dst[e];
  const float score = s_src[s] + s_dst[d];
  const float lr = score > 0.f ? score : LRELU_SLOPE * score;
  const float ee = expf(-lr);
  const float hv = __bfloat162float(h[(size_t)d * OUT_F + lane]);
  atomicAdd(&hprime[(size_t)s * OUT_F + lane], ee * hv);
  if (lane == 0) atomicAdd(&rowsum[s], ee);
}

__global__ __launch_bounds__(256) void finalize_kernel(
    float* __restrict__ hprime, const float* __restrict__ rowsum) {
  const size_t i = (size_t)blockIdx.x * blockDim.x + threadIdx.x;
  const float v = hprime[i] / rowsum[i >> 6];
  hprime[i] = v > 0.f ? v : expm1f(v);
}

extern "C" void kernel_launch(void* const* d_in, const int* in_sizes, int n_in,
                              void* d_out, int out_size, void* d_ws, size_t ws_size,
                              hipStream_t stream) {
  const float* in = (const float*)d_in[0];
  const int* edge = (const int*)d_in[1];
  const float* W = (const float*)d_in[2];
  const float* a = (const float*)d_in[3];
  float* out = (float*)d_out;

  const int* src = edge;
  const int* dst = edge + N_EDGES;

  // common workspace: h(bf16) + s_src + s_dst = 13.6 MB
  char* p = (char*)d_ws;
  __hip_bfloat16* h = (__hip_bfloat16*)p; p += (size_t)N_NODES * OUT_F * 2;
  float* s_src = (float*)p;               p += (size_t)N_NODES * 4;
  float* s_dst = (float*)p;               p += (size_t)N_NODES * 4;

  // CSR extras: sorted_dst 12.8M + counts/offsets/cursor/blocksums ~1.6M
  const size_t CSR_NEED =
      (size_t)N_NODES * OUT_F * 2 + (size_t)N_NODES * 4 * 2 +   // common
      (size_t)N_EDGES * 4 +                                      // sorted_dst
      (size_t)N_NODES * 4 +                                      // counts
      (size_t)(N_NODES + 1) * 4 + 12 +                           // offsets(+pad)
      (size_t)N_NODES * 4 +                                      // cursor
      256 * 4;                                                   // blocksums

  gemm_h_kernel<<<N_NODES / 32, 256, 0, stream>>>(in, W, a, h, s_src, s_dst);

  if (ws_size >= CSR_NEED) {
    int* sorted_dst = (int*)p;  p += (size_t)N_EDGES * 4;
    int* counts = (int*)p;      p += (size_t)N_NODES * 4;
    int* offsets = (int*)p;     p += (size_t)(N_NODES + 1) * 4 + 12;
    int* cursor = (int*)p;      p += (size_t)N_NODES * 4;
    int* blocksums = (int*)p;   p += 256 * 4;

    hipMemsetAsync(counts, 0, (size_t)N_NODES * 4, stream);
    hist_kernel<<<(N_EDGES + 255) / 256, 256, 0, stream>>>(src, counts);
    scan1_kernel<<<SCAN_NBLK, SCAN_B, 0, stream>>>(counts, offsets, blocksums);
    scan2_kernel<<<1, 128, 0, stream>>>(blocksums);
    scan3_kernel<<<SCAN_NBLK, SCAN_B, 0, stream>>>(counts, blocksums, offsets,
                                                   cursor);
    scatter_kernel<<<(N_EDGES + 255) / 256, 256, 0, stream>>>(src, dst, cursor,
                                                              sorted_dst);
    node_aggregate_kernel<<<N_NODES / 4, 256, 0, stream>>>(
        offsets, sorted_dst, s_src, s_dst, h, out);
  } else {
    // atomic fallback (round-1 proven structure)
    float* rowsum = (float*)p;  p += (size_t)N_NODES * 4;
    hipMemsetAsync(out, 0, (size_t)N_NODES * OUT_F * 4, stream);
    hipMemsetAsync(rowsum, 0, (size_t)N_NODES * 4, stream);
    edge_atomic_kernel<<<(N_EDGES + 3) / 4, 256, 0, stream>>>(
        src, dst, h, s_src, s_dst, out, rowsum);
    finalize_kernel<<<(N_NODES * OUT_F) / 256, 256, 0, stream>>>(out, rowsum);
  }
}